// Round 5
// baseline (118.419 us; speedup 1.0000x reference)
//
#include <hip/hip_runtime.h>

namespace {

constexpr int GV   = 48;
constexpr int NV   = 8;
constexpr int NH   = 27;
constexpr int NW   = 27;
constexpr int L    = NH * NW;     // 729
constexpr int C    = 1152;
constexpr int CD   = 288;
constexpr int NPTS = NV * L;      // 5832
constexpr int NVOX = GV * GV * GV;// 110592

typedef __attribute__((ext_vector_type(8))) short short8;
typedef __attribute__((ext_vector_type(4))) float f32x4;

__device__ __forceinline__ unsigned short f2bf(float x) {
    unsigned u = __float_as_uint(x);
    unsigned r = u + 0x7fffu + ((u >> 16) & 1u);   // round-to-nearest-even
    return (unsigned short)(r >> 16);
}

// Per-point prep: zero this point's voxel cell in sums, record flat index,
// count points per voxel. (cnt must be pre-zeroed via memset.)
__global__ __launch_bounds__(CD) void k_prep(const int* __restrict__ coords,
                                             float* __restrict__ sums,
                                             float* __restrict__ cnt,
                                             int* __restrict__ flat) {
    int p = blockIdx.x;
    int c0 = coords[p * 3 + 0], c1 = coords[p * 3 + 1], c2 = coords[p * 3 + 2];
    int fl = (c0 * GV + c1) * GV + c2;
    sums[(size_t)fl * CD + threadIdx.x] = 0.f;
    if (threadIdx.x == 0) {
        flat[p] = fl;
        atomicAdd(&cnt[fl], 1.0f);
    }
}

// f32 -> bf16 bulk convert, 8 elems/thread.
__global__ __launch_bounds__(256) void k_cvt_bf16(const float* __restrict__ in,
                                                  unsigned short* __restrict__ out,
                                                  int n8) {
    int i = blockIdx.x * 256 + threadIdx.x;
    if (i >= n8) return;
    const float4* p = reinterpret_cast<const float4*>(in + (size_t)i * 8);
    float4 a = p[0], b = p[1];
    short8 h;
    h[0] = (short)f2bf(a.x); h[1] = (short)f2bf(a.y);
    h[2] = (short)f2bf(a.z); h[3] = (short)f2bf(a.w);
    h[4] = (short)f2bf(b.x); h[5] = (short)f2bf(b.y);
    h[6] = (short)f2bf(b.z); h[7] = (short)f2bf(b.w);
    *reinterpret_cast<short8*>(out + (size_t)i * 8) = h;
}

// Both weight transposes in one launch. z=0: wdt[n][k]=bf16(w_down[k][n]) with
// K=C,N=CD; z=1: wut[n][k]=bf16(w_up[k][n]) with K=CD,N=C.
__global__ __launch_bounds__(256) void k_transpose_cvt2(const float* __restrict__ Wd,
                                                        const float* __restrict__ Wu,
                                                        unsigned short* __restrict__ Wdt,
                                                        unsigned short* __restrict__ Wut) {
    __shared__ float t[32][33];
    const int tid = threadIdx.x;
    const float* W; unsigned short* Wt; int K, N, kb, nb;
    if (blockIdx.z == 0) {
        W = Wd; Wt = Wdt; K = C;  N = CD;
        kb = blockIdx.x * 32; nb = blockIdx.y * 32;
    } else {
        W = Wu; Wt = Wut; K = CD; N = C;
        kb = blockIdx.y * 32; nb = blockIdx.x * 32;
    }
#pragma unroll
    for (int i = 0; i < 4; ++i) {
        int r = (tid >> 5) + i * 8;
        int c = tid & 31;
        t[r][c] = W[(size_t)(kb + r) * N + nb + c];
    }
    __syncthreads();
#pragma unroll
    for (int i = 0; i < 4; ++i) {
        int r = (tid >> 5) + i * 8;
        int c = tid & 31;
        Wt[(size_t)(nb + r) * K + kb + c] = f2bf(t[c][r]);
    }
}

__device__ __forceinline__ float gelu_tanh(float a) {
    float a3 = a * a * a;
    float inner = 0.7978845608028654f * (a + 0.044715f * a3);
    return 0.5f * a * (1.0f + tanhf(inner));
}

// Depthwise 3x3x3 conv at gathered voxels only, + gelu.
__global__ __launch_bounds__(CD) void k_conv3_gather(const int* __restrict__ coords,
                                                     const float* __restrict__ sums,
                                                     const float* __restrict__ cnt,
                                                     const float* __restrict__ w3,
                                                     float* __restrict__ ptf) {
    int p = blockIdx.x;
    int t = threadIdx.x;
    int c0 = coords[p * 3 + 0], c1 = coords[p * 3 + 1], c2 = coords[p * 3 + 2];
    float acc = 0.f;
#pragma unroll
    for (int dz = 0; dz < 3; ++dz) {
        int z = c0 + dz - 1;
        if ((unsigned)z >= (unsigned)GV) continue;
#pragma unroll
        for (int dy = 0; dy < 3; ++dy) {
            int y = c1 + dy - 1;
            if ((unsigned)y >= (unsigned)GV) continue;
#pragma unroll
            for (int dx = 0; dx < 3; ++dx) {
                int x2 = c2 + dx - 1;
                if ((unsigned)x2 >= (unsigned)GV) continue;
                int n = (z * GV + y) * GV + x2;
                float cv = cnt[n];
                if (cv > 0.f) {
                    float w = w3[t * 27 + dz * 9 + dy * 3 + dx];
                    acc += w * (sums[(size_t)n * CD + t] / cv);
                }
            }
        }
    }
    ptf[(size_t)p * CD + t] = gelu_tanh(acc);
}

// Depthwise 3x3 conv2d over (V,27,27,CD); emits bf16 (GEMM2's A matrix).
__global__ __launch_bounds__(CD) void k_conv2(const float* __restrict__ ptf,
                                              const float* __restrict__ w2,
                                              unsigned short* __restrict__ sm) {
    int p = blockIdx.x;
    int t = threadIdx.x;
    int v = p / L;
    int rem = p - v * L;
    int y = rem / NW;
    int x = rem - y * NW;
    float acc = 0.f;
#pragma unroll
    for (int dy = 0; dy < 3; ++dy) {
        int yy = y + dy - 1;
        if ((unsigned)yy >= (unsigned)NH) continue;
#pragma unroll
        for (int dx = 0; dx < 3; ++dx) {
            int xx = x + dx - 1;
            if ((unsigned)xx >= (unsigned)NW) continue;
            acc += w2[t * 9 + dy * 3 + dx] *
                   ptf[((size_t)v * L + yy * NW + xx) * CD + t];
        }
    }
    sm[(size_t)p * CD + t] = f2bf(acc);
}

// Swizzled LDS element offset for a [rows][32] bf16 tile. slot = 16B unit (0..3).
__device__ __forceinline__ int swz(int row, int slot) {
    return row * 32 + ((slot ^ ((row >> 1) & 3)) << 3);
}

// bf16 MFMA GEMM, all-bf16 staging (pure 16B copies), double-buffered LDS,
// register prefetch one tile ahead, ONE barrier per K-step, bijective XCD
// swizzle for L2 locality.  Cout[M,N] = A[M,K] * Bt[N,K]^T (+Cin).
// BN=96, BK=32, 256 thr = 4 waves (2x2). BM in {32, 64, 128}.
// ATOMIC: epilogue scatters rows into Cout[flat[row]*N + col] via atomicAdd.
template<int BM, bool ATOMIC>
__global__ __launch_bounds__(256) void k_gemm_mfma(const unsigned short* __restrict__ A,
                                                   const unsigned short* __restrict__ Bt,
                                                   const float* __restrict__ Cin,
                                                   const int* __restrict__ flat,
                                                   float* __restrict__ Cout,
                                                   int M, int N, int K) {
    constexpr int MR = BM / 32;
    __shared__ unsigned short As[2][BM * 32];
    __shared__ unsigned short Bs[2][96 * 32];

    const int tid  = threadIdx.x;
    const int lane = tid & 63;
    const int wave = tid >> 6;
    const int wm   = wave >> 1;
    const int wn   = wave & 1;

    // bijective XCD-chunked block swizzle (m204): consecutive original ids
    // (which share the A row-panel) land on the same XCD.
    const int nwg = gridDim.x * gridDim.y;
    int lid = blockIdx.y * gridDim.x + blockIdx.x;
    {
        const int q = nwg >> 3, r = nwg & 7;
        const int xcd = lid & 7, pos = lid >> 3;
        lid = (xcd < r ? xcd * (q + 1) : r * (q + 1) + (xcd - r) * q) + pos;
    }
    const int m0 = (lid / gridDim.x) * BM;
    const int n0 = (lid % gridDim.x) * 96;

    // A staging: BM*4 16B-units over 256 threads.
    int a_row0, a_slot;
    bool has_a;
    if constexpr (BM == 32)      { a_row0 = (tid - 128) >> 2; has_a = (tid >= 128); }
    else                         { a_row0 = tid >> 2;         has_a = true; }
    a_slot = tid & 3;
    const bool avalid0 = has_a && (m0 + a_row0) < M;
    const bool avalid1 = (BM == 128) && (m0 + a_row0 + 64) < M;

    // B staging: 384 units: all threads one, tid<128 a second.
    const int b0_row = tid >> 2, b0_slot = tid & 3;
    const int b1_row = 64 + (tid >> 2);
    const bool has_b1 = (tid < 128);

    short8 areg0, areg1, breg0, breg1;

    auto LOAD = [&](int kt) {
        const int kb = kt * 32;
        areg0 = (short8){0,0,0,0,0,0,0,0};
        if (avalid0)
            areg0 = *reinterpret_cast<const short8*>(A + (size_t)(m0 + a_row0) * K + kb + a_slot * 8);
        if constexpr (BM == 128) {
            areg1 = (short8){0,0,0,0,0,0,0,0};
            if (avalid1)
                areg1 = *reinterpret_cast<const short8*>(A + (size_t)(m0 + a_row0 + 64) * K + kb + a_slot * 8);
        }
        breg0 = *reinterpret_cast<const short8*>(Bt + (size_t)(n0 + b0_row) * K + kb + b0_slot * 8);
        if (has_b1)
            breg1 = *reinterpret_cast<const short8*>(Bt + (size_t)(n0 + b1_row) * K + kb + b0_slot * 8);
    };

    auto STAGE = [&](int buf) {
        if (has_a)
            *reinterpret_cast<short8*>(&As[buf][swz(a_row0, a_slot)]) = areg0;
        if constexpr (BM == 128)
            *reinterpret_cast<short8*>(&As[buf][swz(a_row0 + 64, a_slot)]) = areg1;
        *reinterpret_cast<short8*>(&Bs[buf][swz(b0_row, b0_slot)]) = breg0;
        if (has_b1)
            *reinterpret_cast<short8*>(&Bs[buf][swz(b1_row, b0_slot)]) = breg1;
    };

    f32x4 acc[MR][3];
#pragma unroll
    for (int m = 0; m < MR; ++m)
#pragma unroll
        for (int n = 0; n < 3; ++n) acc[m][n] = (f32x4){0.f, 0.f, 0.f, 0.f};

    const int nsteps = K / 32;

    LOAD(0);
    STAGE(0);
    if (nsteps > 1) LOAD(1);
    __syncthreads();

    const int kgrp = lane >> 4;
    const int lr   = lane & 15;

    for (int kt = 0; kt < nsteps; ++kt) {
        const int cur = kt & 1;
        short8 afrag[MR], bfrag[3];
#pragma unroll
        for (int m = 0; m < MR; ++m) {
            int r = wm * (BM / 2) + m * 16 + lr;
            afrag[m] = *reinterpret_cast<const short8*>(&As[cur][swz(r, kgrp)]);
        }
#pragma unroll
        for (int n = 0; n < 3; ++n) {
            int c = wn * 48 + n * 16 + lr;
            bfrag[n] = *reinterpret_cast<const short8*>(&Bs[cur][swz(c, kgrp)]);
        }
        if (kt + 1 < nsteps) {
            STAGE(cur ^ 1);
            if (kt + 2 < nsteps) LOAD(kt + 2);
        }
#pragma unroll
        for (int m = 0; m < MR; ++m)
#pragma unroll
            for (int n = 0; n < 3; ++n)
                acc[m][n] = __builtin_amdgcn_mfma_f32_16x16x32_bf16(
                    afrag[m], bfrag[n], acc[m][n], 0, 0, 0);
        if (kt + 1 < nsteps) __syncthreads();
    }

    const int rq = lane >> 4;
    if constexpr (ATOMIC) {
        int fl[MR][4];
#pragma unroll
        for (int m = 0; m < MR; ++m) {
            int rbase = m0 + wm * (BM / 2) + m * 16 + rq * 4;
#pragma unroll
            for (int r = 0; r < 4; ++r)
                fl[m][r] = (rbase + r < M) ? flat[rbase + r] : -1;
        }
#pragma unroll
        for (int m = 0; m < MR; ++m)
#pragma unroll
            for (int n = 0; n < 3; ++n) {
                int col = n0 + wn * 48 + n * 16 + lr;
#pragma unroll
                for (int r = 0; r < 4; ++r)
                    if (fl[m][r] >= 0)
                        atomicAdd(&Cout[(size_t)fl[m][r] * N + col], acc[m][n][r]);
            }
    } else {
#pragma unroll
        for (int m = 0; m < MR; ++m) {
            int rbase = m0 + wm * (BM / 2) + m * 16 + rq * 4;
#pragma unroll
            for (int n = 0; n < 3; ++n) {
                int col = n0 + wn * 48 + n * 16 + lr;
#pragma unroll
                for (int r = 0; r < 4; ++r) {
                    int row = rbase + r;
                    if (row < M) {
                        float v = acc[m][n][r];
                        if (Cin) v += Cin[(size_t)row * N + col];
                        Cout[(size_t)row * N + col] = v;
                    }
                }
            }
        }
    }
}

}  // namespace

extern "C" void kernel_launch(void* const* d_in, const int* in_sizes, int n_in,
                              void* d_out, int out_size, void* d_ws, size_t ws_size,
                              hipStream_t stream) {
    const float* hs     = (const float*)d_in[0];
    const int*   coords = (const int*)d_in[1];
    const float* w_down = (const float*)d_in[2];
    const float* w3     = (const float*)d_in[3];
    const float* w2     = (const float*)d_in[4];
    const float* w_up   = (const float*)d_in[5];
    float* out = (float*)d_out;

    float* ws   = (float*)d_ws;
    float* cnt  = ws;                                   // NVOX f32
    float* sums = cnt + NVOX;                           // NVOX*CD f32
    float* ptf  = sums + (size_t)NVOX * CD;             // NPTS*CD f32
    int*   flat = (int*)(ptf + (size_t)NPTS * CD);      // NPTS int
    unsigned short* hs_bf = (unsigned short*)(flat + NPTS);   // NPTS*C
    unsigned short* smbuf = hs_bf + (size_t)NPTS * C;   // NPTS*CD bf16
    unsigned short* wdt   = smbuf + (size_t)NPTS * CD;  // [CD][C] bf16
    unsigned short* wut   = wdt + (size_t)CD * C;       // [C][CD] bf16

    // 0. zero cnt; prep (zero touched sums cells, flat idx, counts)
    hipMemsetAsync(cnt, 0, NVOX * sizeof(float), stream);
    k_prep<<<dim3(NPTS), dim3(CD), 0, stream>>>(coords, sums, cnt, flat);

    // 1. precompute bf16 operands
    k_cvt_bf16<<<dim3((NPTS * C / 8 + 255) / 256), dim3(256), 0, stream>>>(
        hs, hs_bf, NPTS * C / 8);
    k_transpose_cvt2<<<dim3(C / 32, CD / 32, 2), dim3(256), 0, stream>>>(
        w_down, w_up, wdt, wut);

    // 2. GEMM1 fused with voxel scatter: sums[flat[p]*CD+c] += (hs @ w_down)[p][c]
    k_gemm_mfma<32, true><<<dim3(CD / 96, (NPTS + 31) / 32), dim3(256), 0, stream>>>(
        hs_bf, wdt, nullptr, flat, sums, NPTS, CD, C);

    // 3. depthwise conv3d + gelu at gathered voxels
    k_conv3_gather<<<dim3(NPTS), dim3(CD), 0, stream>>>(coords, sums, cnt, w3, ptf);

    // 4. depthwise conv2d, bf16 out
    k_conv2<<<dim3(NPTS), dim3(CD), 0, stream>>>(ptf, w2, smbuf);

    // 5. out = hs + sm @ w_up   (5832x288 * 288x1152)  BM=128 -> 12x46 = 552 blocks
    k_gemm_mfma<128, false><<<dim3(C / 96, (NPTS + 127) / 128), dim3(256), 0, stream>>>(
        smbuf, wut, hs, nullptr, out, NPTS, C, CD);
}

// Round 6
// 104.378 us; speedup vs baseline: 1.1345x; 1.1345x over previous
//
#include <hip/hip_runtime.h>

namespace {

constexpr int GV   = 48;
constexpr int NV   = 8;
constexpr int NH   = 27;
constexpr int NW   = 27;
constexpr int L    = NH * NW;     // 729
constexpr int C    = 1152;
constexpr int CD   = 288;
constexpr int NPTS = NV * L;      // 5832
constexpr int NVOX = GV * GV * GV;// 110592

typedef __attribute__((ext_vector_type(8))) short short8;
typedef __attribute__((ext_vector_type(4))) float f32x4;

__device__ __forceinline__ unsigned short f2bf(float x) {
    unsigned u = __float_as_uint(x);
    unsigned r = u + 0x7fffu + ((u >> 16) & 1u);   // round-to-nearest-even
    return (unsigned short)(r >> 16);
}
__device__ __forceinline__ float bf2f(unsigned short h) {
    return __uint_as_float(((unsigned)h) << 16);
}

// ---------------- combo kernel: all independent prep work in ONE dispatch ----
// ranges: [0,NB_CVT) hs->bf16 | [..+324) w_down^T | [..+324) w_up^T |
//         [..+432) zero cnt | [..+NPTS) zero touched sums + flat[]
constexpr int NB_CVT  = (NPTS * C / 8 + 255) / 256;   // 3281
constexpr int NB_T    = (C / 32) * (CD / 32);         // 324
constexpr int NB_ZC   = (NVOX + 255) / 256;           // 432
constexpr int B_T1   = NB_CVT;
constexpr int B_T2   = B_T1 + NB_T;
constexpr int B_ZC   = B_T2 + NB_T;
constexpr int B_PREP = B_ZC + NB_ZC;
constexpr int NB_ALL = B_PREP + NPTS;

__global__ __launch_bounds__(256) void k_combo(const float* __restrict__ hs,
                                               const int* __restrict__ coords,
                                               const float* __restrict__ w_down,
                                               const float* __restrict__ w_up,
                                               unsigned short* __restrict__ hs_bf,
                                               unsigned short* __restrict__ wdt,
                                               unsigned short* __restrict__ wut,
                                               float* __restrict__ cnt,
                                               float* __restrict__ sums,
                                               int* __restrict__ flat) {
    const int b   = blockIdx.x;
    const int tid = threadIdx.x;
    if (b < NB_CVT) {
        int i = b * 256 + tid;
        if (i < NPTS * C / 8) {
            const float4* p = reinterpret_cast<const float4*>(hs + (size_t)i * 8);
            float4 a = p[0], bb = p[1];
            short8 h;
            h[0] = (short)f2bf(a.x);  h[1] = (short)f2bf(a.y);
            h[2] = (short)f2bf(a.z);  h[3] = (short)f2bf(a.w);
            h[4] = (short)f2bf(bb.x); h[5] = (short)f2bf(bb.y);
            h[6] = (short)f2bf(bb.z); h[7] = (short)f2bf(bb.w);
            *reinterpret_cast<short8*>(hs_bf + (size_t)i * 8) = h;
        }
    } else if (b < B_ZC) {
        // transpose+cvt: Wt[n][k] = bf16(W[k][n])
        __shared__ float t[32][33];
        const float* W; unsigned short* Wt; int K, N, kb, nb;
        if (b < B_T2) {
            int bb = b - B_T1;                 // W=w_down: K=C, N=CD
            W = w_down; Wt = wdt; K = C; N = CD;
            kb = (bb % (C / 32)) * 32; nb = (bb / (C / 32)) * 32;
        } else {
            int bb = b - B_T2;                 // W=w_up: K=CD, N=C
            W = w_up; Wt = wut; K = CD; N = C;
            nb = (bb % (C / 32)) * 32; kb = (bb / (C / 32)) * 32;
        }
#pragma unroll
        for (int i = 0; i < 4; ++i) {
            int r = (tid >> 5) + i * 8, c = tid & 31;
            t[r][c] = W[(size_t)(kb + r) * N + nb + c];
        }
        __syncthreads();
#pragma unroll
        for (int i = 0; i < 4; ++i) {
            int r = (tid >> 5) + i * 8, c = tid & 31;
            Wt[(size_t)(nb + r) * K + kb + c] = f2bf(t[c][r]);
        }
    } else if (b < B_PREP) {
        int i = (b - B_ZC) * 256 + tid;
        if (i < NVOX) cnt[i] = 0.f;
    } else {
        int p = b - B_PREP;
        int c0 = coords[p * 3 + 0], c1 = coords[p * 3 + 1], c2 = coords[p * 3 + 2];
        int fl = (c0 * GV + c1) * GV + c2;
        if (tid == 0) flat[p] = fl;
        for (int i = tid; i < CD; i += 256) sums[(size_t)fl * CD + i] = 0.f;
    }
}

__device__ __forceinline__ float gelu_tanh(float a) {
    float a3 = a * a * a;
    float inner = 0.7978845608028654f * (a + 0.044715f * a3);
    return 0.5f * a * (1.0f + tanhf(inner));
}

// Depthwise 3x3x3 conv at gathered voxels only, + gelu; bf16 out.
__global__ __launch_bounds__(CD) void k_conv3_gather(const int* __restrict__ coords,
                                                     const float* __restrict__ sums,
                                                     const float* __restrict__ cnt,
                                                     const float* __restrict__ w3,
                                                     unsigned short* __restrict__ ptf) {
    int p = blockIdx.x;
    int t = threadIdx.x;
    int c0 = coords[p * 3 + 0], c1 = coords[p * 3 + 1], c2 = coords[p * 3 + 2];
    float acc = 0.f;
#pragma unroll
    for (int dz = 0; dz < 3; ++dz) {
        int z = c0 + dz - 1;
        if ((unsigned)z >= (unsigned)GV) continue;
#pragma unroll
        for (int dy = 0; dy < 3; ++dy) {
            int y = c1 + dy - 1;
            if ((unsigned)y >= (unsigned)GV) continue;
#pragma unroll
            for (int dx = 0; dx < 3; ++dx) {
                int x2 = c2 + dx - 1;
                if ((unsigned)x2 >= (unsigned)GV) continue;
                int n = (z * GV + y) * GV + x2;
                float cv = cnt[n];
                if (cv > 0.f) {
                    float w = w3[t * 27 + dz * 9 + dy * 3 + dx];
                    acc += w * (sums[(size_t)n * CD + t] / cv);
                }
            }
        }
    }
    ptf[(size_t)p * CD + t] = f2bf(gelu_tanh(acc));
}

// Depthwise 3x3 conv2d over (V,27,27,CD); bf16 in/out.
__global__ __launch_bounds__(CD) void k_conv2(const unsigned short* __restrict__ ptf,
                                              const float* __restrict__ w2,
                                              unsigned short* __restrict__ sm) {
    int p = blockIdx.x;
    int t = threadIdx.x;
    int v = p / L;
    int rem = p - v * L;
    int y = rem / NW;
    int x = rem - y * NW;
    float acc = 0.f;
#pragma unroll
    for (int dy = 0; dy < 3; ++dy) {
        int yy = y + dy - 1;
        if ((unsigned)yy >= (unsigned)NH) continue;
#pragma unroll
        for (int dx = 0; dx < 3; ++dx) {
            int xx = x + dx - 1;
            if ((unsigned)xx >= (unsigned)NW) continue;
            acc += w2[t * 9 + dy * 3 + dx] *
                   bf2f(ptf[((size_t)v * L + yy * NW + xx) * CD + t]);
        }
    }
    sm[(size_t)p * CD + t] = f2bf(acc);
}

// Swizzled LDS element offset for a [rows][32] bf16 tile. slot = 16B unit (0..3).
__device__ __forceinline__ int swz(int row, int slot) {
    return row * 32 + ((slot ^ ((row >> 1) & 3)) << 3);
}

// bf16 MFMA GEMM, all-bf16 staging, double-buffered LDS, register prefetch one
// tile ahead, ONE barrier per K-step, bijective XCD swizzle.
// Cout[M,N] = A[M,K] * Bt[N,K]^T (+Cin). BN=96, BK=32, 256 thr = 4 waves (2x2).
// ATOMIC: scatter rows into Cout[flat[row]*N+col] via atomicAdd; blocks with
// n0==0 also count rows into cnt[flat[row]] (one thread per row).
template<int BM, bool ATOMIC>
__global__ __launch_bounds__(256) void k_gemm_mfma(const unsigned short* __restrict__ A,
                                                   const unsigned short* __restrict__ Bt,
                                                   const float* __restrict__ Cin,
                                                   const int* __restrict__ flat,
                                                   float* __restrict__ cnt,
                                                   float* __restrict__ Cout,
                                                   int M, int N, int K) {
    constexpr int MR = BM / 32;
    __shared__ unsigned short As[2][BM * 32];
    __shared__ unsigned short Bs[2][96 * 32];

    const int tid  = threadIdx.x;
    const int lane = tid & 63;
    const int wave = tid >> 6;
    const int wm   = wave >> 1;
    const int wn   = wave & 1;

    // bijective XCD-chunked block swizzle (m204)
    const int nwg = gridDim.x * gridDim.y;
    int lid = blockIdx.y * gridDim.x + blockIdx.x;
    {
        const int q = nwg >> 3, r = nwg & 7;
        const int xcd = lid & 7, pos = lid >> 3;
        lid = (xcd < r ? xcd * (q + 1) : r * (q + 1) + (xcd - r) * q) + pos;
    }
    const int m0 = (lid / gridDim.x) * BM;
    const int n0 = (lid % gridDim.x) * 96;

    // A staging: BM*4 16B-units over 256 threads.
    int a_row0;
    bool has_a;
    if constexpr (BM == 32) { a_row0 = (tid - 128) >> 2; has_a = (tid >= 128); }
    else                    { a_row0 = tid >> 2;         has_a = true; }
    const int a_slot = tid & 3;
    const bool avalid0 = has_a && (m0 + a_row0) < M;

    // B staging: 384 units: all threads one, tid<128 a second.
    const int b0_row = tid >> 2, b0_slot = tid & 3;
    const int b1_row = 64 + (tid >> 2);
    const bool has_b1 = (tid < 128);

    short8 areg0, breg0, breg1;

    auto LOAD = [&](int kt) {
        const int kb = kt * 32;
        areg0 = (short8){0,0,0,0,0,0,0,0};
        if (avalid0)
            areg0 = *reinterpret_cast<const short8*>(A + (size_t)(m0 + a_row0) * K + kb + a_slot * 8);
        breg0 = *reinterpret_cast<const short8*>(Bt + (size_t)(n0 + b0_row) * K + kb + b0_slot * 8);
        if (has_b1)
            breg1 = *reinterpret_cast<const short8*>(Bt + (size_t)(n0 + b1_row) * K + kb + b0_slot * 8);
    };

    auto STAGE = [&](int buf) {
        if (has_a)
            *reinterpret_cast<short8*>(&As[buf][swz(a_row0, a_slot)]) = areg0;
        *reinterpret_cast<short8*>(&Bs[buf][swz(b0_row, b0_slot)]) = breg0;
        if (has_b1)
            *reinterpret_cast<short8*>(&Bs[buf][swz(b1_row, b0_slot)]) = breg1;
    };

    f32x4 acc[MR][3];
#pragma unroll
    for (int m = 0; m < MR; ++m)
#pragma unroll
        for (int n = 0; n < 3; ++n) acc[m][n] = (f32x4){0.f, 0.f, 0.f, 0.f};

    const int nsteps = K / 32;

    LOAD(0);
    STAGE(0);
    if (nsteps > 1) LOAD(1);
    __syncthreads();

    const int kgrp = lane >> 4;
    const int lr   = lane & 15;

    for (int kt = 0; kt < nsteps; ++kt) {
        const int cur = kt & 1;
        short8 afrag[MR], bfrag[3];
#pragma unroll
        for (int m = 0; m < MR; ++m) {
            int r = wm * (BM / 2) + m * 16 + lr;
            afrag[m] = *reinterpret_cast<const short8*>(&As[cur][swz(r, kgrp)]);
        }
#pragma unroll
        for (int n = 0; n < 3; ++n) {
            int c = wn * 48 + n * 16 + lr;
            bfrag[n] = *reinterpret_cast<const short8*>(&Bs[cur][swz(c, kgrp)]);
        }
        if (kt + 1 < nsteps) {
            STAGE(cur ^ 1);
            if (kt + 2 < nsteps) LOAD(kt + 2);
        }
#pragma unroll
        for (int m = 0; m < MR; ++m)
#pragma unroll
            for (int n = 0; n < 3; ++n)
                acc[m][n] = __builtin_amdgcn_mfma_f32_16x16x32_bf16(
                    afrag[m], bfrag[n], acc[m][n], 0, 0, 0);
        if (kt + 1 < nsteps) __syncthreads();
    }

    const int rq = lane >> 4;
    if constexpr (ATOMIC) {
        int fl[MR][4];
#pragma unroll
        for (int m = 0; m < MR; ++m) {
            int rbase = m0 + wm * (BM / 2) + m * 16 + rq * 4;
#pragma unroll
            for (int r = 0; r < 4; ++r)
                fl[m][r] = (rbase + r < M) ? flat[rbase + r] : -1;
        }
        // count each row once (first column-tile, one lane per row)
        if (n0 == 0 && wn == 0 && lr == 0) {
#pragma unroll
            for (int m = 0; m < MR; ++m)
#pragma unroll
                for (int r = 0; r < 4; ++r)
                    if (fl[m][r] >= 0) atomicAdd(&cnt[fl[m][r]], 1.0f);
        }
#pragma unroll
        for (int m = 0; m < MR; ++m)
#pragma unroll
            for (int n = 0; n < 3; ++n) {
                int col = n0 + wn * 48 + n * 16 + lr;
#pragma unroll
                for (int r = 0; r < 4; ++r)
                    if (fl[m][r] >= 0)
                        atomicAdd(&Cout[(size_t)fl[m][r] * N + col], acc[m][n][r]);
            }
    } else {
#pragma unroll
        for (int m = 0; m < MR; ++m) {
            int rbase = m0 + wm * (BM / 2) + m * 16 + rq * 4;
#pragma unroll
            for (int n = 0; n < 3; ++n) {
                int col = n0 + wn * 48 + n * 16 + lr;
#pragma unroll
                for (int r = 0; r < 4; ++r) {
                    int row = rbase + r;
                    if (row < M) {
                        float v = acc[m][n][r];
                        if (Cin) v += Cin[(size_t)row * N + col];
                        Cout[(size_t)row * N + col] = v;
                    }
                }
            }
        }
    }
}

}  // namespace

extern "C" void kernel_launch(void* const* d_in, const int* in_sizes, int n_in,
                              void* d_out, int out_size, void* d_ws, size_t ws_size,
                              hipStream_t stream) {
    const float* hs     = (const float*)d_in[0];
    const int*   coords = (const int*)d_in[1];
    const float* w_down = (const float*)d_in[2];
    const float* w3     = (const float*)d_in[3];
    const float* w2     = (const float*)d_in[4];
    const float* w_up   = (const float*)d_in[5];
    float* out = (float*)d_out;

    float* ws   = (float*)d_ws;
    float* cnt  = ws;                                   // NVOX f32
    float* sums = cnt + NVOX;                           // NVOX*CD f32
    int*   flat = (int*)(sums + (size_t)NVOX * CD);     // NPTS int
    unsigned short* hs_bf = (unsigned short*)(flat + NPTS);   // NPTS*C bf16
    unsigned short* ptf   = hs_bf + (size_t)NPTS * C;   // NPTS*CD bf16
    unsigned short* smbuf = ptf + (size_t)NPTS * CD;    // NPTS*CD bf16
    unsigned short* wdt   = smbuf + (size_t)NPTS * CD;  // [CD][C] bf16
    unsigned short* wut   = wdt + (size_t)CD * C;       // [C][CD] bf16

    // 1. all prep in one dispatch: cvt, transposes, zero cnt, zero touched, flat
    k_combo<<<dim3(NB_ALL), dim3(256), 0, stream>>>(
        hs, coords, w_down, w_up, hs_bf, wdt, wut, cnt, sums, flat);

    // 2. GEMM1 fused with voxel scatter + cnt counting
    k_gemm_mfma<32, true><<<dim3(CD / 96, (NPTS + 31) / 32), dim3(256), 0, stream>>>(
        hs_bf, wdt, nullptr, flat, cnt, sums, NPTS, CD, C);

    // 3. depthwise conv3d + gelu at gathered voxels (bf16 out)
    k_conv3_gather<<<dim3(NPTS), dim3(CD), 0, stream>>>(coords, sums, cnt, w3, ptf);

    // 4. depthwise conv2d (bf16 in/out)
    k_conv2<<<dim3(NPTS), dim3(CD), 0, stream>>>(ptf, w2, smbuf);

    // 5. out = hs + sm @ w_up   BM=64 -> 12x92 = 1104 blocks
    k_gemm_mfma<64, false><<<dim3(C / 96, (NPTS + 63) / 64), dim3(256), 0, stream>>>(
        smbuf, wut, hs, nullptr, nullptr, out, NPTS, C, CD);
}